// Round 6
// baseline (462.573 us; speedup 1.0000x reference)
//
#include <hip/hip_runtime.h>
#include <hip/hip_bf16.h>
#include <math.h>

// Problem constants
#define BN    8        // b*n = 4*2
#define H     480
#define W     640
#define CH    128
#define OH    120      // conv out h (stride 4, pad 3, k 7)
#define OW    160      // conv out w
#define P     192
#define PS    7
#define GH    16
#define GW    16
#define PH    30       // cell height  (480/16)
#define PW    40       // cell width   (640/16)

// ---------------------------------------------------------------------------
// Kernel 1: conv encoder fmap (1->128ch, 7x7, stride 4, pad 3, +b, ReLU).
// 32x8 output tile staged in LDS; 4 channel groups of 32 (grid 2400 blocks)
// and 4 channels in flight per thread -> 4 independent FMA chains (ILP) to
// beat dependent-FMA latency. Per-channel k=0..48 order: bit-exact.
// ---------------------------------------------------------------------------
__global__ __launch_bounds__(256) void conv_enc(
    const float* __restrict__ f,
    const float* __restrict__ wf, const float* __restrict__ bf,
    float* __restrict__ fmap)
{
    __shared__ float s[35][132];       // rows iy_base..+34, cols ix_base..+131

    int blk = blockIdx.x;              // 600 = 5 x 15 x 8
    int tx = blk % 5;
    int ty = (blk / 5) % 15;
    int b  = blk / 75;
    int ox0 = tx * 32, oy0 = ty * 8;
    int c0 = blockIdx.y * 32;
    int tid = threadIdx.x;
    int ix_base = 4 * ox0 - 3, iy_base = 4 * oy0 - 3;
    const float* fb = f + (size_t)b * H * W;

    for (int i = tid; i < 35 * 132; i += 256) {
        int r = i / 132, c = i % 132;
        int gy = iy_base + r, gx = ix_base + c;
        s[r][c] = (gy >= 0 && gy < H && gx >= 0 && gx < W)
                ? fb[(size_t)gy * W + gx] : 0.0f;
    }
    __syncthreads();

    int oxl = tid & 31, oyl = tid >> 5;
    float in[49];
    #pragma unroll
    for (int ky = 0; ky < 7; ky++) {
        const float4 a  = *(const float4*)&s[4 * oyl + ky][4 * oxl];
        const float4 b4 = *(const float4*)&s[4 * oyl + ky][4 * oxl + 4];
        in[ky * 7 + 0] = a.x;  in[ky * 7 + 1] = a.y;
        in[ky * 7 + 2] = a.z;  in[ky * 7 + 3] = a.w;
        in[ky * 7 + 4] = b4.x; in[ky * 7 + 5] = b4.y;
        in[ky * 7 + 6] = b4.z;
    }

    int ox = ox0 + oxl, oy = oy0 + oyl;
    size_t obase = (size_t)b * CH * (OH * OW) + (size_t)oy * OW + ox;
    for (int cc = 0; cc < 32; cc += 4) {
        int c = c0 + cc;
        const float* w0 = wf + c * 49;
        const float* w1 = w0 + 49;
        const float* w2 = w0 + 98;
        const float* w3 = w0 + 147;
        float a0 = bf[c], a1 = bf[c + 1], a2 = bf[c + 2], a3 = bf[c + 3];
        #pragma unroll
        for (int k = 0; k < 49; k++) {
            float x = in[k];
            a0 = fmaf(w0[k], x, a0);
            a1 = fmaf(w1[k], x, a1);
            a2 = fmaf(w2[k], x, a2);
            a3 = fmaf(w3[k], x, a3);
        }
        fmap[obase + (size_t)(c    ) * (OH * OW)] = fmaxf(a0, 0.0f);
        fmap[obase + (size_t)(c + 1) * (OH * OW)] = fmaxf(a1, 0.0f);
        fmap[obase + (size_t)(c + 2) * (OH * OW)] = fmaxf(a2, 0.0f);
        fmap[obase + (size_t)(c + 3) * (OH * OW)] = fmaxf(a3, 0.0f);
    }
}

// ---------------------------------------------------------------------------
// Kernel 2: fused Harris + per-cell argmax. One block per grid cell (30x40).
// !!! ACCUMULATION-ORDER-SENSITIVE: each pixel's 7x7 box sum MUST be the
// direct row-major (ky,kx) chain of individual adds. Separable / row-sum
// reassociation flips argmax ties (rounds 1 & 4: absmax 468). The register
// blocking below shares LDS READS only — every pixel still executes its own
// exact 49-add chain per array. !!!
// ---------------------------------------------------------------------------
__global__ __launch_bounds__(256) void harris_cell(
    const float* __restrict__ f, float* __restrict__ cval, int* __restrict__ cidx)
{
    __shared__ float sf[37][48];
    __shared__ float dxx[36][48], dyy[36][48], dxy[36][48];
    __shared__ float sv[256];
    __shared__ int   si[256];

    int cell = blockIdx.x;            // b*256 + gh*16 + gw
    int b  = cell >> 8;
    int ci = cell & 255;
    int gh = ci >> 4, gw = ci & 15;
    int cy0 = gh * PH, cx0 = gw * PW;
    const float* fb = f + (size_t)b * H * W;
    int tid = threadIdx.x;

    // load f rows [cy0-3, cy0+33] (37), cols [cx0-3, cx0+43] (47), clamped
    for (int i = tid; i < 37 * 47; i += 256) {
        int r = i / 47, c = i % 47;
        int y = min(max(cy0 - 3 + r, 0), H - 1);
        int x = min(max(cx0 - 3 + c, 0), W - 1);
        sf[r][c] = fb[(size_t)y * W + x];
    }
    __syncthreads();

    // derivative products at rows [cy0-3, cy0+32] (36), cols [cx0-3, cx0+42] (46)
    for (int i = tid; i < 36 * 46; i += 256) {
        int r = i / 46, c = i % 46;
        int y = cy0 - 3 + r;
        int x = cx0 - 3 + c;
        float vxx = 0.0f, vyy = 0.0f, vxy = 0.0f;
        if (y >= 0 && y < H && x >= 0 && x < W) {
            int xa = (x == W - 1) ? (x - 2) : x;    // dx[639] = dx[637]
            int ya = (y == H - 1) ? (y - 2) : y;    // dy[479] = dy[477]
            int lx = xa - (cx0 - 3);
            int ly = ya - (cy0 - 3);
            float dxv = sf[r][lx + 1] - sf[r][lx];
            float dyv = sf[ly + 1][c] - sf[ly][c];
            vxx = dxv * dxv;
            vyy = dyv * dyv;
            vxy = dxv * dyv;
        }
        dxx[r][c] = vxx; dyy[r][c] = vyy; dxy[r][c] = vxy;
    }
    __syncthreads();

    // Register-blocked box sums: thread = (col, 6-pixel vertical group).
    // Load each derivative row once (21 regs), add each value individually
    // to every covered pixel in exact (ky,kx) row-major order.
    float best = -INFINITY;
    int   bidx = 0x7fffffff;
    if (tid < 200) {
        int col = tid % 40;           // ix
        int grp = tid / 40;           // iy0 = grp*6, pixels iy0..iy0+5
        int iy0 = grp * 6;
        float axx[6] = {0,0,0,0,0,0};
        float ayy[6] = {0,0,0,0,0,0};
        float axy[6] = {0,0,0,0,0,0};
        #pragma unroll
        for (int r = 0; r < 12; r++) {
            float vxx[7], vyy[7], vxy[7];
            #pragma unroll
            for (int kx = 0; kx < 7; kx++) {
                vxx[kx] = dxx[iy0 + r][col + kx];
                vyy[kx] = dyy[iy0 + r][col + kx];
                vxy[kx] = dxy[iy0 + r][col + kx];
            }
            #pragma unroll
            for (int p = 0; p < 6; p++) {
                if (r - p >= 0 && r - p <= 6) {   // pixel p uses rows p..p+6
                    #pragma unroll
                    for (int kx = 0; kx < 7; kx++) {
                        axx[p] += vxx[kx];
                        ayy[p] += vyy[kx];
                        axy[p] += vxy[kx];
                    }
                }
            }
        }
        #pragma unroll
        for (int p = 0; p < 6; p++) {
            float Ixx = axx[p] / 49.0f;
            float Iyy = ayy[p] / 49.0f;
            float Ixy = axy[p] / 49.0f;
            float resp = (Ixx * Iyy - Ixy * Ixy) / (Ixx + Iyy + 1e-8f);
            int idx = (iy0 + p) * PW + col;
            if (resp > best) { best = resp; bidx = idx; }
        }
    }

    sv[tid] = best;
    si[tid] = bidx;
    __syncthreads();
    for (int s = 128; s > 0; s >>= 1) {
        if (tid < s) {
            float ov = sv[tid + s];
            int   oi = si[tid + s];
            if (ov > sv[tid] || (ov == sv[tid] && oi < si[tid])) {
                sv[tid] = ov; si[tid] = oi;
            }
        }
        __syncthreads();
    }
    if (tid == 0) { cval[cell] = sv[0]; cidx[cell] = si[0]; }
}

// ---------------------------------------------------------------------------
// Kernel 3: stable top-192 of 256 cell maxima per batch via O(256^2) ranking
// ---------------------------------------------------------------------------
__global__ __launch_bounds__(256) void topk_coords(
    const float* __restrict__ cval, const int* __restrict__ cidx,
    float* __restrict__ coords)
{
    int b = blockIdx.x;
    int j = threadIdx.x;
    __shared__ float v[256];
    v[j] = cval[b * 256 + j];
    __syncthreads();
    float vj = v[j];
    int rank = 0;
    for (int k = 0; k < 256; k++) {
        float vk = v[k];
        rank += (vk > vj) || (vk == vj && k < j);
    }
    if (rank < P) {
        int ii = cidx[b * 256 + j];
        int gh = j >> 4, gw = j & 15;
        int y = ii / PW + gh * PH;
        int x = ii % PW + gw * PW;
        coords[((size_t)b * P + rank) * 2 + 0] = (float)x;
        coords[((size_t)b * P + rank) * 2 + 1] = (float)y;
    }
}

// ---------------------------------------------------------------------------
// Kernel 4: patches. One block per (b,p) point. All 49 taps share one
// bilinear fraction; stage the 8x8x128 fmap window in LDS.
// patches_c: on-the-fly second conv at the 4 corner pixels.
// ---------------------------------------------------------------------------
__global__ __launch_bounds__(256) void patches_kern(
    const float* __restrict__ coords,
    const float* __restrict__ fmap,
    const float* __restrict__ frame,
    const float* __restrict__ wc, const float* __restrict__ bc,
    float* __restrict__ pf, float* __restrict__ pc)
{
    __shared__ float sfm[CH][64];      // 8 rows x 8 cols per channel, 32 KB
    __shared__ float sf2[14][16];
    __shared__ float vq[CH][5];

    int bp = blockIdx.x;               // 0 .. BN*P
    int b = bp / P;
    float cx = coords[(size_t)bp * 2 + 0] * 0.25f;   // /DS, exact
    float cy = coords[(size_t)bp * 2 + 1] * 0.25f;
    int tid = threadIdx.x;

    int X0 = (int)floorf(cx), Y0 = (int)floorf(cy);
    float wx = cx - (float)X0, wy = cy - (float)Y0;
    float w00 = (1.0f - wx) * (1.0f - wy);
    float w10 = wx * (1.0f - wy);
    float w01 = (1.0f - wx) * wy;
    float w11 = wx * wy;

    // stage fmap window rows [Y0-3, Y0+4], cols [X0-3, X0+4], all channels
    const float* fm = fmap + (size_t)b * CH * (OH * OW);
    for (int i = tid; i < CH * 64; i += 256) {
        int ch = i >> 6;
        int off = i & 63;
        int r = off >> 3, c = off & 7;
        int gy = Y0 - 3 + r, gx = X0 - 3 + c;
        sfm[ch][off] = (gy >= 0 && gy < OH && gx >= 0 && gx < OW)
                     ? fm[(size_t)ch * (OH * OW) + gy * OW + gx] : 0.0f;
    }

    // stage 14x14 input patch for the on-the-fly conv (zero outside image)
    int ix0 = 4 * X0 - 3, iy0 = 4 * Y0 - 3;
    const float* frb = frame + (size_t)b * H * W;
    for (int i = tid; i < 14 * 14; i += 256) {
        int r = i / 14, c = i % 14;
        int y = iy0 + r, x = ix0 + c;
        sf2[r][c] = (y >= 0 && y < H && x >= 0 && x < W)
                  ? frb[(size_t)y * W + x] : 0.0f;
    }
    __syncthreads();

    // ---- patches_f: bilinear from LDS ----
    size_t pfbase = (size_t)bp * CH * 49;
    for (int idx = tid; idx < CH * 49; idx += 256) {
        int c = idx / 49;
        int k = idx - c * 49;
        int ky = k / 7, kx = k - ky * 7;
        int o = ky * 8 + kx;
        float acc = w00 * sfm[c][o]
                  + w10 * sfm[c][o + 1]
                  + w01 * sfm[c][o + 8]
                  + w11 * sfm[c][o + 9];
        pf[pfbase + idx] = acc;
    }

    // ---- on-the-fly second conv at the 4 corner pixels ----
    for (int idx = tid; idx < 512; idx += 256) {
        int q = idx & 3;            // (qx,qy) = (q&1, q>>1)
        int c = idx >> 2;
        int qx = q & 1, qy = q >> 1;
        const float* wcc = wc + c * 49;
        float acc = bc[c];
        #pragma unroll
        for (int ky = 0; ky < 7; ky++) {
            #pragma unroll
            for (int kx = 0; kx < 7; kx++)
                acc = fmaf(wcc[ky * 7 + kx], sf2[4 * qy + ky][4 * qx + kx], acc);
        }
        vq[c][q] = fmaxf(acc, 0.0f);
    }
    __syncthreads();

    // ---- patches_c: bilinear combine with boundary masks ----
    float m00 = (X0 >= 0 && X0 < OW && Y0 >= 0 && Y0 < OH) ? 1.0f : 0.0f;
    float m10 = (X0 + 1 >= 0 && X0 + 1 < OW && Y0 >= 0 && Y0 < OH) ? 1.0f : 0.0f;
    float m01 = (X0 >= 0 && X0 < OW && Y0 + 1 >= 0 && Y0 + 1 < OH) ? 1.0f : 0.0f;
    float m11 = (X0 + 1 >= 0 && X0 + 1 < OW && Y0 + 1 >= 0 && Y0 + 1 < OH) ? 1.0f : 0.0f;
    if (tid < CH) {
        float acc = w00 * m00 * vq[tid][0] + w10 * m10 * vq[tid][1]
                  + w01 * m01 * vq[tid][2] + w11 * m11 * vq[tid][3];
        pc[(size_t)bp * CH + tid] = acc;
    }
}

// ---------------------------------------------------------------------------
// Launch
// ---------------------------------------------------------------------------
extern "C" void kernel_launch(void* const* d_in, const int* in_sizes, int n_in,
                              void* d_out, int out_size, void* d_ws, size_t ws_size,
                              hipStream_t stream)
{
    const float* frame = (const float*)d_in[0];
    const float* w_f   = (const float*)d_in[1];
    const float* b_f   = (const float*)d_in[2];
    const float* w_c   = (const float*)d_in[3];
    const float* b_c   = (const float*)d_in[4];

    float* out = (float*)d_out;
    // output layout: coords | patches_f | patches_c | fmap
    const size_t coords_sz = (size_t)BN * P * 2;                 // 3072
    const size_t pf_sz     = (size_t)BN * P * CH * 49;           // 9,633,792
    const size_t pc_sz     = (size_t)BN * P * CH;                // 196,608
    float* coords = out;
    float* pf     = out + coords_sz;
    float* pc     = out + coords_sz + pf_sz;
    float* fmap   = out + coords_sz + pf_sz + pc_sz;

    // workspace: only cell argmax state (16 KB)
    float* cval = (float*)d_ws;                                  // 2048 f
    int*   cidx = (int*)(cval + BN * 256);                       // 2048 i

    dim3 cg(600, 4);
    conv_enc<<<cg, 256, 0, stream>>>(frame, w_f, b_f, fmap);

    harris_cell<<<BN * 256, 256, 0, stream>>>(frame, cval, cidx);

    topk_coords<<<BN, 256, 0, stream>>>(cval, cidx, coords);

    patches_kern<<<BN * P, 256, 0, stream>>>(
        coords, fmap, frame, w_c, b_c, pf, pc);
}

// Round 7
// 258.048 us; speedup vs baseline: 1.7926x; 1.7926x over previous
//
#include <hip/hip_runtime.h>
#include <hip/hip_bf16.h>
#include <math.h>

// Problem constants
#define BN    8        // b*n = 4*2
#define H     480
#define W     640
#define CH    128
#define OH    120      // conv out h (stride 4, pad 3, k 7)
#define OW    160      // conv out w
#define P     192
#define PS    7
#define GH    16
#define GW    16
#define PH    30       // cell height  (480/16)
#define PW    40       // cell width   (640/16)

// ---------------------------------------------------------------------------
// Kernel 1: conv encoder fmap (1->128ch, 7x7, stride 4, pad 3, +b, ReLU).
// One thread per output pixel x 8-channel group; grid 600x16 = 9600 blocks.
// !!! Inner loop MUST stay one-channel-at-a-time with a single wave-uniform
// weight pointer: that's what lets the compiler hoist the 49 weights into
// SGPRs (s_load) per channel. Multi-channel ILP through several pointers
// regressed 94 -> 282 us (round 6). Parallelism (wave count) is what hides
// the per-channel weight-load waits. !!!
// ---------------------------------------------------------------------------
__global__ __launch_bounds__(256) void conv_enc(
    const float* __restrict__ f,
    const float* __restrict__ wf, const float* __restrict__ bf,
    float* __restrict__ fmap)
{
    int pix = blockIdx.x * blockDim.x + threadIdx.x;
    if (pix >= BN * OH * OW) return;
    int c0 = blockIdx.y * 8;             // channel group
    int ox = pix % OW;
    int t  = pix / OW;
    int oy = t % OH;
    int b  = t / OH;

    const float* fb = f + (size_t)b * H * W;
    int iy0 = 4 * oy - 3;
    int ix0 = 4 * ox - 3;

    float in[49];
    if (oy > 0 && ox > 0) {
        // interior: 4*oy-3 >= 1, max 4*119+3 = 479 -> always in range
        #pragma unroll
        for (int ky = 0; ky < 7; ky++) {
            const float* row = fb + (iy0 + ky) * W + ix0;
            #pragma unroll
            for (int kx = 0; kx < 7; kx++) in[ky * 7 + kx] = row[kx];
        }
    } else {
        #pragma unroll
        for (int ky = 0; ky < 7; ky++) {
            int iy = iy0 + ky;
            #pragma unroll
            for (int kx = 0; kx < 7; kx++) {
                int ix = ix0 + kx;
                in[ky * 7 + kx] = (iy >= 0 && ix >= 0) ? fb[iy * W + ix] : 0.0f;
            }
        }
    }

    size_t obase = (size_t)b * CH * (OH * OW) + (size_t)oy * OW + ox;
    for (int c = c0; c < c0 + 8; c++) {
        const float* wfc = wf + c * 49;
        float af = bf[c];
        #pragma unroll
        for (int k = 0; k < 49; k++) af = fmaf(wfc[k], in[k], af);
        fmap[obase + (size_t)c * (OH * OW)] = fmaxf(af, 0.0f);
    }
}

// ---------------------------------------------------------------------------
// Kernel 2: fused Harris + per-cell argmax. One block per grid cell (30x40).
// !!! ACCUMULATION-ORDER-SENSITIVE: each pixel's 7x7 box sum MUST be the
// direct row-major (ky,kx) chain of individual adds. Separable / row-sum
// reassociation flips argmax ties (rounds 1 & 4: absmax 468). The register
// blocking below shares LDS READS only — every pixel still executes its own
// exact 49-add chain per array. !!!
// ---------------------------------------------------------------------------
__global__ __launch_bounds__(256) void harris_cell(
    const float* __restrict__ f, float* __restrict__ cval, int* __restrict__ cidx)
{
    __shared__ float sf[37][48];
    __shared__ float dxx[36][48], dyy[36][48], dxy[36][48];
    __shared__ float sv[256];
    __shared__ int   si[256];

    int cell = blockIdx.x;            // b*256 + gh*16 + gw
    int b  = cell >> 8;
    int ci = cell & 255;
    int gh = ci >> 4, gw = ci & 15;
    int cy0 = gh * PH, cx0 = gw * PW;
    const float* fb = f + (size_t)b * H * W;
    int tid = threadIdx.x;

    // load f rows [cy0-3, cy0+33] (37), cols [cx0-3, cx0+43] (47), clamped
    for (int i = tid; i < 37 * 47; i += 256) {
        int r = i / 47, c = i % 47;
        int y = min(max(cy0 - 3 + r, 0), H - 1);
        int x = min(max(cx0 - 3 + c, 0), W - 1);
        sf[r][c] = fb[(size_t)y * W + x];
    }
    __syncthreads();

    // derivative products at rows [cy0-3, cy0+32] (36), cols [cx0-3, cx0+42] (46)
    for (int i = tid; i < 36 * 46; i += 256) {
        int r = i / 46, c = i % 46;
        int y = cy0 - 3 + r;
        int x = cx0 - 3 + c;
        float vxx = 0.0f, vyy = 0.0f, vxy = 0.0f;
        if (y >= 0 && y < H && x >= 0 && x < W) {
            int xa = (x == W - 1) ? (x - 2) : x;    // dx[639] = dx[637]
            int ya = (y == H - 1) ? (y - 2) : y;    // dy[479] = dy[477]
            int lx = xa - (cx0 - 3);
            int ly = ya - (cy0 - 3);
            float dxv = sf[r][lx + 1] - sf[r][lx];
            float dyv = sf[ly + 1][c] - sf[ly][c];
            vxx = dxv * dxv;
            vyy = dyv * dyv;
            vxy = dxv * dyv;
        }
        dxx[r][c] = vxx; dyy[r][c] = vyy; dxy[r][c] = vxy;
    }
    __syncthreads();

    // Register-blocked box sums: thread = (col, 6-pixel vertical group).
    // Load each derivative row once (21 regs), add each value individually
    // to every covered pixel in exact (ky,kx) row-major order.
    float best = -INFINITY;
    int   bidx = 0x7fffffff;
    if (tid < 200) {
        int col = tid % 40;           // ix
        int grp = tid / 40;           // iy0 = grp*6, pixels iy0..iy0+5
        int iy0 = grp * 6;
        float axx[6] = {0,0,0,0,0,0};
        float ayy[6] = {0,0,0,0,0,0};
        float axy[6] = {0,0,0,0,0,0};
        #pragma unroll
        for (int r = 0; r < 12; r++) {
            float vxx[7], vyy[7], vxy[7];
            #pragma unroll
            for (int kx = 0; kx < 7; kx++) {
                vxx[kx] = dxx[iy0 + r][col + kx];
                vyy[kx] = dyy[iy0 + r][col + kx];
                vxy[kx] = dxy[iy0 + r][col + kx];
            }
            #pragma unroll
            for (int p = 0; p < 6; p++) {
                if (r - p >= 0 && r - p <= 6) {   // pixel p uses rows p..p+6
                    #pragma unroll
                    for (int kx = 0; kx < 7; kx++) {
                        axx[p] += vxx[kx];
                        ayy[p] += vyy[kx];
                        axy[p] += vxy[kx];
                    }
                }
            }
        }
        #pragma unroll
        for (int p = 0; p < 6; p++) {
            float Ixx = axx[p] / 49.0f;
            float Iyy = ayy[p] / 49.0f;
            float Ixy = axy[p] / 49.0f;
            float resp = (Ixx * Iyy - Ixy * Ixy) / (Ixx + Iyy + 1e-8f);
            int idx = (iy0 + p) * PW + col;
            if (resp > best) { best = resp; bidx = idx; }
        }
    }

    sv[tid] = best;
    si[tid] = bidx;
    __syncthreads();
    for (int s = 128; s > 0; s >>= 1) {
        if (tid < s) {
            float ov = sv[tid + s];
            int   oi = si[tid + s];
            if (ov > sv[tid] || (ov == sv[tid] && oi < si[tid])) {
                sv[tid] = ov; si[tid] = oi;
            }
        }
        __syncthreads();
    }
    if (tid == 0) { cval[cell] = sv[0]; cidx[cell] = si[0]; }
}

// ---------------------------------------------------------------------------
// Kernel 3: stable top-192 of 256 cell maxima per batch via O(256^2) ranking
// ---------------------------------------------------------------------------
__global__ __launch_bounds__(256) void topk_coords(
    const float* __restrict__ cval, const int* __restrict__ cidx,
    float* __restrict__ coords)
{
    int b = blockIdx.x;
    int j = threadIdx.x;
    __shared__ float v[256];
    v[j] = cval[b * 256 + j];
    __syncthreads();
    float vj = v[j];
    int rank = 0;
    for (int k = 0; k < 256; k++) {
        float vk = v[k];
        rank += (vk > vj) || (vk == vj && k < j);
    }
    if (rank < P) {
        int ii = cidx[b * 256 + j];
        int gh = j >> 4, gw = j & 15;
        int y = ii / PW + gh * PH;
        int x = ii % PW + gw * PW;
        coords[((size_t)b * P + rank) * 2 + 0] = (float)x;
        coords[((size_t)b * P + rank) * 2 + 1] = (float)y;
    }
}

// ---------------------------------------------------------------------------
// Kernel 4: patches. One block per (b,p) point. All 49 taps share one
// bilinear fraction; stage the 8x8x128 fmap window in LDS.
// patches_c: on-the-fly second conv at the 4 corner pixels.
// ---------------------------------------------------------------------------
__global__ __launch_bounds__(256) void patches_kern(
    const float* __restrict__ coords,
    const float* __restrict__ fmap,
    const float* __restrict__ frame,
    const float* __restrict__ wc, const float* __restrict__ bc,
    float* __restrict__ pf, float* __restrict__ pc)
{
    __shared__ float sfm[CH][64];      // 8 rows x 8 cols per channel, 32 KB
    __shared__ float sf2[14][16];
    __shared__ float vq[CH][5];

    int bp = blockIdx.x;               // 0 .. BN*P
    int b = bp / P;
    float cx = coords[(size_t)bp * 2 + 0] * 0.25f;   // /DS, exact
    float cy = coords[(size_t)bp * 2 + 1] * 0.25f;
    int tid = threadIdx.x;

    int X0 = (int)floorf(cx), Y0 = (int)floorf(cy);
    float wx = cx - (float)X0, wy = cy - (float)Y0;
    float w00 = (1.0f - wx) * (1.0f - wy);
    float w10 = wx * (1.0f - wy);
    float w01 = (1.0f - wx) * wy;
    float w11 = wx * wy;

    // stage fmap window rows [Y0-3, Y0+4], cols [X0-3, X0+4], all channels
    const float* fm = fmap + (size_t)b * CH * (OH * OW);
    for (int i = tid; i < CH * 64; i += 256) {
        int ch = i >> 6;
        int off = i & 63;
        int r = off >> 3, c = off & 7;
        int gy = Y0 - 3 + r, gx = X0 - 3 + c;
        sfm[ch][off] = (gy >= 0 && gy < OH && gx >= 0 && gx < OW)
                     ? fm[(size_t)ch * (OH * OW) + gy * OW + gx] : 0.0f;
    }

    // stage 14x14 input patch for the on-the-fly conv (zero outside image)
    int ix0 = 4 * X0 - 3, iy0 = 4 * Y0 - 3;
    const float* frb = frame + (size_t)b * H * W;
    for (int i = tid; i < 14 * 14; i += 256) {
        int r = i / 14, c = i % 14;
        int y = iy0 + r, x = ix0 + c;
        sf2[r][c] = (y >= 0 && y < H && x >= 0 && x < W)
                  ? frb[(size_t)y * W + x] : 0.0f;
    }
    __syncthreads();

    // ---- patches_f: bilinear from LDS ----
    size_t pfbase = (size_t)bp * CH * 49;
    for (int idx = tid; idx < CH * 49; idx += 256) {
        int c = idx / 49;
        int k = idx - c * 49;
        int ky = k / 7, kx = k - ky * 7;
        int o = ky * 8 + kx;
        float acc = w00 * sfm[c][o]
                  + w10 * sfm[c][o + 1]
                  + w01 * sfm[c][o + 8]
                  + w11 * sfm[c][o + 9];
        pf[pfbase + idx] = acc;
    }

    // ---- on-the-fly second conv at the 4 corner pixels ----
    for (int idx = tid; idx < 512; idx += 256) {
        int q = idx & 3;            // (qx,qy) = (q&1, q>>1)
        int c = idx >> 2;
        int qx = q & 1, qy = q >> 1;
        const float* wcc = wc + c * 49;
        float acc = bc[c];
        #pragma unroll
        for (int ky = 0; ky < 7; ky++) {
            #pragma unroll
            for (int kx = 0; kx < 7; kx++)
                acc = fmaf(wcc[ky * 7 + kx], sf2[4 * qy + ky][4 * qx + kx], acc);
        }
        vq[c][q] = fmaxf(acc, 0.0f);
    }
    __syncthreads();

    // ---- patches_c: bilinear combine with boundary masks ----
    float m00 = (X0 >= 0 && X0 < OW && Y0 >= 0 && Y0 < OH) ? 1.0f : 0.0f;
    float m10 = (X0 + 1 >= 0 && X0 + 1 < OW && Y0 >= 0 && Y0 < OH) ? 1.0f : 0.0f;
    float m01 = (X0 >= 0 && X0 < OW && Y0 + 1 >= 0 && Y0 + 1 < OH) ? 1.0f : 0.0f;
    float m11 = (X0 + 1 >= 0 && X0 + 1 < OW && Y0 + 1 >= 0 && Y0 + 1 < OH) ? 1.0f : 0.0f;
    if (tid < CH) {
        float acc = w00 * m00 * vq[tid][0] + w10 * m10 * vq[tid][1]
                  + w01 * m01 * vq[tid][2] + w11 * m11 * vq[tid][3];
        pc[(size_t)bp * CH + tid] = acc;
    }
}

// ---------------------------------------------------------------------------
// Launch
// ---------------------------------------------------------------------------
extern "C" void kernel_launch(void* const* d_in, const int* in_sizes, int n_in,
                              void* d_out, int out_size, void* d_ws, size_t ws_size,
                              hipStream_t stream)
{
    const float* frame = (const float*)d_in[0];
    const float* w_f   = (const float*)d_in[1];
    const float* b_f   = (const float*)d_in[2];
    const float* w_c   = (const float*)d_in[3];
    const float* b_c   = (const float*)d_in[4];

    float* out = (float*)d_out;
    // output layout: coords | patches_f | patches_c | fmap
    const size_t coords_sz = (size_t)BN * P * 2;                 // 3072
    const size_t pf_sz     = (size_t)BN * P * CH * 49;           // 9,633,792
    const size_t pc_sz     = (size_t)BN * P * CH;                // 196,608
    float* coords = out;
    float* pf     = out + coords_sz;
    float* pc     = out + coords_sz + pf_sz;
    float* fmap   = out + coords_sz + pf_sz + pc_sz;

    // workspace: only cell argmax state (16 KB)
    float* cval = (float*)d_ws;                                  // 2048 f
    int*   cidx = (int*)(cval + BN * 256);                       // 2048 i

    dim3 cg((BN * OH * OW) / 256, 16);
    conv_enc<<<cg, 256, 0, stream>>>(frame, w_f, b_f, fmap);

    harris_cell<<<BN * 256, 256, 0, stream>>>(frame, cval, cidx);

    topk_coords<<<BN, 256, 0, stream>>>(cval, cidx, coords);

    patches_kern<<<BN * P, 256, 0, stream>>>(
        coords, fmap, frame, w_c, b_c, pf, pc);
}